// Round 9
// baseline (394.553 us; speedup 1.0000x reference)
//
#include <hip/hip_runtime.h>
#include <hip/hip_bf16.h>

#define D 128
#define EPSV 1e-5f

static inline int cdiv(int a, int b) { return (a + b - 1) / b; }

// bf16 RNE pack
__device__ __forceinline__ unsigned short f2bf(float f) {
    unsigned int x = __float_as_uint(f);
    unsigned int r = x + 0x7fffu + ((x >> 16) & 1u);
    return (unsigned short)(r >> 16);
}

// ---------------- edge preprocessing (fully deterministic) ----------------

__global__ void hist_kernel(const int* __restrict__ col, int* __restrict__ cnt, int E_) {
    int e = blockIdx.x * blockDim.x + threadIdx.x;
    if (e >= E_) return;
    atomicAdd(&cnt[col[e]], 1);  // int atomics: result order-independent
}

__global__ void scan_chunk_sums(const int* __restrict__ cnt, int* __restrict__ bsum, int n) {
    __shared__ int sm[1024];
    int i = blockIdx.x * 1024 + threadIdx.x;
    sm[threadIdx.x] = (i < n) ? cnt[i] : 0;
    __syncthreads();
    for (int off = 512; off > 0; off >>= 1) {
        if (threadIdx.x < off) sm[threadIdx.x] += sm[threadIdx.x + off];
        __syncthreads();
    }
    if (threadIdx.x == 0) bsum[blockIdx.x] = sm[0];
}

__global__ void scan_final(const int* __restrict__ cnt, const int* __restrict__ bsum, int nbk,
                           int* __restrict__ offs, int* __restrict__ cursor, int n, int E_) {
    __shared__ int sm[1024];
    __shared__ int sbo;
    int tid = threadIdx.x;
    int bv = (tid < nbk && tid < blockIdx.x) ? bsum[tid] : 0;
    sm[tid] = bv;
    __syncthreads();
    for (int off = 512; off > 0; off >>= 1) {
        if (tid < off) sm[tid] += sm[tid + off];
        __syncthreads();
    }
    if (tid == 0) {
        sbo = sm[0];
        if (blockIdx.x == 0) offs[n] = E_;
    }
    __syncthreads();
    int i = blockIdx.x * 1024 + tid;
    int v = (i < n) ? cnt[i] : 0;
    sm[tid] = v;
    __syncthreads();
    for (int off = 1; off < 1024; off <<= 1) {
        int t = (tid >= off) ? sm[tid - off] : 0;
        __syncthreads();
        sm[tid] += t;
        __syncthreads();
    }
    if (i < n) {
        int excl = sm[tid] - v + sbo;
        offs[i] = excl;
        cursor[i] = excl;
    }
}

// scatter packed (edge_id<<32 | src_row) into CSR slots
__global__ void scatter_pack(const int* __restrict__ row, const int* __restrict__ col,
                             int* __restrict__ cursor, long long* __restrict__ pk, int E_) {
    int e = blockIdx.x * blockDim.x + threadIdx.x;
    if (e >= E_) return;
    int c = col[e];
    int r = row[e];
    int p = atomicAdd(&cursor[c], 1);
    pk[p] = ((long long)e << 32) | (unsigned int)r;
}

// wave-level bitonic sort per node (key = edge id); writes csr=(r, ea),
// deterministic tree-sum for deg -> dis.
__global__ __launch_bounds__(256) void sort_deg_kernel(const long long* __restrict__ pk,
                                                       const int* __restrict__ offs,
                                                       const float* __restrict__ ea,
                                                       float* __restrict__ dis,
                                                       int2* __restrict__ csr, int n) {
    int node = blockIdx.x * 4 + (threadIdx.x >> 6);
    int lane = threadIdx.x & 63;
    if (node >= n) return;
    int p0 = offs[node], p1 = offs[node + 1];
    int deg = p1 - p0;
    if (deg <= 64) {
        long long v = (lane < deg) ? pk[p0 + lane] : 0x7fffffffffffffffLL;
        for (int k = 2; k <= 64; k <<= 1) {
            for (int j = k >> 1; j > 0; j >>= 1) {
                long long partner = __shfl_xor(v, j, 64);
                bool up = ((lane & k) == 0);
                bool keepMin = ((lane & j) == 0);
                long long mn = v < partner ? v : partner;
                long long mx = v < partner ? partner : v;
                v = (up == keepMin) ? mn : mx;
            }
        }
        int e = (int)(v >> 32);
        int r = (int)(v & 0xffffffffLL);
        float av = (lane < deg) ? ea[e] : 0.f;
        if (lane < deg) csr[p0 + lane] = make_int2(r, __float_as_int(av));
        float s = av;
        for (int off = 32; off > 0; off >>= 1) s += __shfl_xor(s, off, 64);
        if (lane == 0) dis[node] = s > 0.f ? rsqrtf(fmaxf(s, EPSV)) : 0.f;
    } else {
        if (lane == 0) {  // deterministic O(d^2) selection fallback (unreachable)
            float dg = 0.f;
            for (int p = p0; p < p1; ++p) {
                long long best = 0x7fffffffffffffffLL;
                for (int q2 = p0; q2 < p1; ++q2) {
                    long long cand = pk[q2];
                    int less = 0;
                    for (int q3 = p0; q3 < p1; ++q3)
                        if (pk[q3] < cand) ++less;
                    if (less == p - p0) { best = cand; break; }
                }
                int e = (int)(best >> 32);
                int r = (int)(best & 0xffffffffLL);
                float av = ea[e];
                csr[p] = make_int2(r, __float_as_int(av));
                dg += av;
            }
            dis[node] = dg > 0.f ? rsqrtf(fmaxf(dg, EPSV)) : 0.f;
        }
    }
}

// finalize weights: (r, ea) -> (r, dis[r]*ea*dis[c])
__global__ __launch_bounds__(256) void fill_w_kernel(const int* __restrict__ offs,
                                                     const float* __restrict__ dis,
                                                     int2* __restrict__ csr, int n) {
    int node = blockIdx.x * 4 + (threadIdx.x >> 6);
    int lane = threadIdx.x & 63;
    if (node >= n) return;
    int p0 = offs[node], p1 = offs[node + 1];
    float dc = dis[node];
    for (int p = p0 + lane; p < p1; p += 64) {
        int2 pr = csr[p];
        float w = dis[pr.x] * __int_as_float(pr.y) * dc;
        csr[p] = make_int2(pr.x, __float_as_int(w));
    }
}

// ---------------- batch norm stats (layer 1: emb gather) ----------------

template <bool GATHER>
__global__ __launch_bounds__(256) void bn_stats(const float* __restrict__ src,
                                                const int* __restrict__ idx,
                                                float* __restrict__ pS,
                                                float* __restrict__ pQ, int n, int NB) {
    int sub = threadIdx.x >> 5;
    int q = threadIdx.x & 31;
    float4 s = make_float4(0, 0, 0, 0), s2 = make_float4(0, 0, 0, 0);
    int stride = gridDim.x * 8;
    int i = blockIdx.x * 8 + sub;
    int r_next = (i < n) ? (GATHER ? idx[i] : i) : 0;
    for (; i < n; i += stride) {
        int r = r_next;
        int i2 = i + stride;
        if (i2 < n) r_next = GATHER ? idx[i2] : i2;
        float4 v = *(const float4*)&src[(long)r * D + q * 4];
        s.x += v.x; s.y += v.y; s.z += v.z; s.w += v.w;
        s2.x += v.x * v.x; s2.y += v.y * v.y; s2.z += v.z * v.z; s2.w += v.w * v.w;
    }
    __shared__ float4 redA[256], redB[256];
    redA[threadIdx.x] = s;
    redB[threadIdx.x] = s2;
    __syncthreads();
    for (int off = 128; off >= 32; off >>= 1) {
        if (threadIdx.x < off) {
            float4 a = redA[threadIdx.x + off], b = redB[threadIdx.x + off];
            redA[threadIdx.x].x += a.x; redA[threadIdx.x].y += a.y;
            redA[threadIdx.x].z += a.z; redA[threadIdx.x].w += a.w;
            redB[threadIdx.x].x += b.x; redB[threadIdx.x].y += b.y;
            redB[threadIdx.x].z += b.z; redB[threadIdx.x].w += b.w;
        }
        __syncthreads();
    }
    if (threadIdx.x < 32) {
        float4 a = redA[threadIdx.x], b = redB[threadIdx.x];
        int bofs = blockIdx.x;
        pS[(q * 4 + 0) * NB + bofs] = a.x;
        pS[(q * 4 + 1) * NB + bofs] = a.y;
        pS[(q * 4 + 2) * NB + bofs] = a.z;
        pS[(q * 4 + 3) * NB + bofs] = a.w;
        pQ[(q * 4 + 0) * NB + bofs] = b.x;
        pQ[(q * 4 + 1) * NB + bofs] = b.y;
        pQ[(q * 4 + 2) * NB + bofs] = b.z;
        pQ[(q * 4 + 3) * NB + bofs] = b.w;
    }
}

__global__ __launch_bounds__(256) void bn_reduce(const float* __restrict__ pS,
                                                 const float* __restrict__ pQ, int nb,
                                                 const float* __restrict__ gamma,
                                                 const float* __restrict__ beta,
                                                 float* __restrict__ scale,
                                                 float* __restrict__ shift, float n) {
    int d = blockIdx.x;
    int tid = threadIdx.x;
    float s = 0.f, q = 0.f;
    for (int b = tid; b < nb; b += 256) {
        s += pS[d * nb + b];
        q += pQ[d * nb + b];
    }
    __shared__ float smS[256], smQ[256];
    smS[tid] = s;
    smQ[tid] = q;
    __syncthreads();
    for (int off = 128; off > 0; off >>= 1) {
        if (tid < off) {
            smS[tid] += smS[tid + off];
            smQ[tid] += smQ[tid + off];
        }
        __syncthreads();
    }
    if (tid == 0) {
        float mean = smS[0] / n;
        float var = smQ[0] / n - mean * mean;
        float rstd = rsqrtf(var + EPSV);
        float sc = gamma[d] * rstd;
        scale[d] = sc;
        shift[d] = beta[d] - mean * sc;
    }
}

// ---------------- GEMM: h = (src*scale+shift) @ W, output bf16 ----------------

template <bool GATHER>
__global__ __launch_bounds__(256) void gemm_bn(const float* __restrict__ src,
                                               const int* __restrict__ idx,
                                               const float* __restrict__ scale,
                                               const float* __restrict__ shift,
                                               const float* __restrict__ W,
                                               unsigned short* __restrict__ outb, int n) {
    __shared__ float xs[64 * 132];  // 33.8 KB
    int tid = threadIdx.x;
    int r0 = blockIdx.x * 64;
    const float4* scale4 = (const float4*)scale;
    const float4* shift4 = (const float4*)shift;
    for (int it = 0; it < 8; ++it) {
        int flat = it * 256 + tid;
        int r = flat >> 5;
        int kq = flat & 31;
        int gr = r0 + r;
        float4 v = make_float4(0.f, 0.f, 0.f, 0.f);
        if (gr < n) {
            int srow = GATHER ? idx[gr] : gr;
            float4 x4 = *(const float4*)&src[(long)srow * D + kq * 4];
            float4 sc = scale4[kq], sh = shift4[kq];
            v = make_float4(x4.x * sc.x + sh.x, x4.y * sc.y + sh.y, x4.z * sc.z + sh.z,
                            x4.w * sc.w + sh.w);
        }
        *(float4*)&xs[r * 132 + kq * 4] = v;
    }
    __syncthreads();
    int cg = tid & 31;
    int rg = tid >> 5;
    float acc[8][4];
#pragma unroll
    for (int j = 0; j < 8; ++j)
#pragma unroll
        for (int q = 0; q < 4; ++q) acc[j][q] = 0.f;
    const float4* Wv = (const float4*)W;
#pragma unroll 2
    for (int k4 = 0; k4 < 128; k4 += 4) {
        float4 wv0 = Wv[(k4 + 0) * 32 + cg];
        float4 wv1 = Wv[(k4 + 1) * 32 + cg];
        float4 wv2 = Wv[(k4 + 2) * 32 + cg];
        float4 wv3 = Wv[(k4 + 3) * 32 + cg];
#pragma unroll
        for (int j = 0; j < 8; ++j) {
            float4 xv = *(const float4*)&xs[(rg * 8 + j) * 132 + k4];
            acc[j][0] += xv.x * wv0.x; acc[j][1] += xv.x * wv0.y;
            acc[j][2] += xv.x * wv0.z; acc[j][3] += xv.x * wv0.w;
            acc[j][0] += xv.y * wv1.x; acc[j][1] += xv.y * wv1.y;
            acc[j][2] += xv.y * wv1.z; acc[j][3] += xv.y * wv1.w;
            acc[j][0] += xv.z * wv2.x; acc[j][1] += xv.z * wv2.y;
            acc[j][2] += xv.z * wv2.z; acc[j][3] += xv.z * wv2.w;
            acc[j][0] += xv.w * wv3.x; acc[j][1] += xv.w * wv3.y;
            acc[j][2] += xv.w * wv3.z; acc[j][3] += xv.w * wv3.w;
        }
    }
#pragma unroll
    for (int j = 0; j < 8; ++j) {
        int gr = r0 + rg * 8 + j;
        if (gr < n) {
            ushort4 o = make_ushort4(f2bf(acc[j][0]), f2bf(acc[j][1]), f2bf(acc[j][2]),
                                     f2bf(acc[j][3]));
            *(ushort4*)&outb[(long)gr * D + cg * 4] = o;
        }
    }
}

// ---------------- aggregation: x[i] = relu(b + sum_e w_e * h[row_e]) ----------------
// bf16 h, 1 node/wave, predicated 8-wide inner loop (no serial tail; dummy
// slots clamp to csr[p0] -> same row, cache-hit, weight 0). STATS variant
// additionally accumulates BN sum/sumsq partials for the NEXT layer.

template <bool STATS>
__global__ __launch_bounds__(256) void agg_kernel(const unsigned int* __restrict__ hw,
                                                  const int2* __restrict__ csr,
                                                  const int* __restrict__ offs,
                                                  const float2* __restrict__ bias2,
                                                  float2* __restrict__ xout, int n,
                                                  float* __restrict__ pS,
                                                  float* __restrict__ pQ, int NB) {
    int lane = threadIdx.x & 63;
    int wv = threadIdx.x >> 6;
    float2 bs = bias2[lane];
    float2 s = make_float2(0.f, 0.f), s2 = make_float2(0.f, 0.f);
    int nGroups = (n + 3) >> 2;
    for (int grp = blockIdx.x; grp < nGroups; grp += gridDim.x) {
        int node = grp * 4 + wv;
        if (node < n) {
            int p0 = offs[node], p1 = offs[node + 1];
            float2 acc = bs;
            for (int p = p0; p < p1; p += 8) {
#pragma unroll
                for (int u = 0; u < 8; ++u) {
                    int pp = p + u;
                    bool ok = pp < p1;
                    int2 e = csr[ok ? pp : p0];
                    unsigned int uu = hw[(long)e.x * 64 + lane];
                    float w = ok ? __int_as_float(e.y) : 0.f;
                    acc.x += w * __uint_as_float(uu << 16);
                    acc.y += w * __uint_as_float(uu & 0xffff0000u);
                }
            }
            float2 x = make_float2(fmaxf(acc.x, 0.f), fmaxf(acc.y, 0.f));
            xout[(long)node * 64 + lane] = x;
            if (STATS) {
                s.x += x.x; s.y += x.y;
                s2.x += x.x * x.x; s2.y += x.y * x.y;
            }
        }
    }
    if (STATS) {
        __shared__ float2 smS[256], smQ[256];
        smS[threadIdx.x] = s;
        smQ[threadIdx.x] = s2;
        __syncthreads();
        if (wv == 0) {
            float2 a = smS[lane], q = smQ[lane];
#pragma unroll
            for (int w2 = 1; w2 < 4; ++w2) {
                float2 b = smS[w2 * 64 + lane], c = smQ[w2 * 64 + lane];
                a.x += b.x; a.y += b.y;
                q.x += c.x; q.y += c.y;
            }
            pS[(2 * lane + 0) * NB + blockIdx.x] = a.x;
            pS[(2 * lane + 1) * NB + blockIdx.x] = a.y;
            pQ[(2 * lane + 0) * NB + blockIdx.x] = q.x;
            pQ[(2 * lane + 1) * NB + blockIdx.x] = q.y;
        }
    }
}

// ---------------- softmax pooling (bounds in-block, 1024 threads) ----------------

__global__ __launch_bounds__(1024) void pool_kernel(const float* __restrict__ tfidf,
                                                    const int* __restrict__ batch,
                                                    const float* __restrict__ x,
                                                    float* __restrict__ out, int n) {
    int g = blockIdx.x;
    int tid = threadIdx.x;
    __shared__ int sbounds[2];
    if (tid < 2) {
        int target = g + tid;
        int lo = 0, hi = n;
        while (lo < hi) {
            int mid = (lo + hi) >> 1;
            if (batch[mid] < target) lo = mid + 1;
            else hi = mid;
        }
        sbounds[tid] = lo;
    }
    __syncthreads();
    int s0 = sbounds[0], s1 = sbounds[1];
    int d = tid & 127, sub = tid >> 7;  // 8-way node split
    __shared__ float red[1024];
    float m = -1e30f;
    for (int i = s0 + tid; i < s1; i += 1024) m = fmaxf(m, tfidf[i]);
    red[tid] = m;
    __syncthreads();
    for (int off = 512; off > 0; off >>= 1) {
        if (tid < off) red[tid] = fmaxf(red[tid], red[tid + off]);
        __syncthreads();
    }
    m = red[0];
    __syncthreads();
    float s = 0.f;
    for (int i = s0 + tid; i < s1; i += 1024) s += __expf(tfidf[i] - m);
    red[tid] = s;
    __syncthreads();
    for (int off = 512; off > 0; off >>= 1) {
        if (tid < off) red[tid] += red[tid + off];
        __syncthreads();
    }
    s = red[0];
    __syncthreads();
    float acc = 0.f;
    for (int i = s0 + sub; i < s1; i += 8) acc += __expf(tfidf[i] - m) * x[(long)i * D + d];
    red[tid] = acc;
    __syncthreads();
    if (tid < 128) {
        float a = 0.f;
#pragma unroll
        for (int w = 0; w < 8; ++w) a += red[w * 128 + d];
        out[g * D + d] = (s1 > s0) ? a / s : 0.f;
    }
}

// ---------------- launch ----------------

extern "C" void kernel_launch(void* const* d_in, const int* in_sizes, int n_in, void* d_out,
                              int out_size, void* d_ws, size_t ws_size, hipStream_t stream) {
    const int N = in_sizes[0];
    const int E = in_sizes[4];
    const int G = out_size / D;
    const int BN_GRID = 768;
    const int AGG_GRID = 2048;

    const int* x_index = (const int*)d_in[0];
    const float* tfidf = (const float*)d_in[1];
    const int* ei_row = (const int*)d_in[2];
    const int* ei_col = ei_row + E;
    const int* batch = (const int*)d_in[3];
    const float* edge_attr = (const float*)d_in[4];
    const float* emb = (const float*)d_in[5];
    const float* gamma1 = (const float*)d_in[6];
    const float* beta1 = (const float*)d_in[7];
    const float* W1 = (const float*)d_in[8];
    const float* b1 = (const float*)d_in[9];
    const float* gamma2 = (const float*)d_in[10];
    const float* beta2 = (const float*)d_in[11];
    const float* W2 = (const float*)d_in[12];
    const float* b2 = (const float*)d_in[13];
    float* out = (float*)d_out;

    // ---- workspace carve (256B aligned) ----
    size_t off = 0;
    char* base = (char*)d_ws;
    auto carve = [&](size_t bytes) -> void* {
        void* p = base + off;
        off = (off + bytes + 255) & ~(size_t)255;
        return p;
    };
    unsigned short* bufA = (unsigned short*)carve((size_t)N * D * 2);  // h (bf16)
    float* bufB = (float*)carve((size_t)N * D * 4);                    // x (layer output)
    long long* pk = (long long*)carve((size_t)E * 8);                  // packed (e, row)
    int2* csr = (int2*)carve((size_t)E * 8);                           // (row, ea) -> (row, w)
    int* cnt = (int*)carve((size_t)N * 4);                             // zeroed each launch
    float* dis = (float*)carve((size_t)N * 4);
    int* offs = (int*)carve((size_t)(N + 1) * 4);
    int* cursor = (int*)carve((size_t)N * 4);
    int* bsum = (int*)carve(64 * 4);
    float* scale1 = (float*)carve(D * 4);
    float* shift1 = (float*)carve(D * 4);
    float* scale2 = (float*)carve(D * 4);
    float* shift2 = (float*)carve(D * 4);
    float* pS = (float*)carve((size_t)AGG_GRID * D * 4);
    float* pQ = (float*)carve((size_t)AGG_GRID * D * 4);
    (void)ws_size;
    (void)n_in;

    hipMemsetAsync(cnt, 0, (size_t)N * 4, stream);

    // ---- edge preprocessing: CSR (deterministic; shared by both layers) ----
    hist_kernel<<<cdiv(E, 256), 256, 0, stream>>>(ei_col, cnt, E);
    int nb = cdiv(N, 1024);
    scan_chunk_sums<<<nb, 1024, 0, stream>>>(cnt, bsum, N);
    scan_final<<<nb, 1024, 0, stream>>>(cnt, bsum, nb, offs, cursor, N, E);
    scatter_pack<<<cdiv(E, 256), 256, 0, stream>>>(ei_row, ei_col, cursor, pk, E);
    sort_deg_kernel<<<cdiv(N, 4), 256, 0, stream>>>(pk, offs, edge_attr, dis, csr, N);
    fill_w_kernel<<<cdiv(N, 4), 256, 0, stream>>>(offs, dis, csr, N);

    // ---- layer 1 ----
    bn_stats<true><<<BN_GRID, 256, 0, stream>>>(emb, x_index, pS, pQ, N, BN_GRID);
    bn_reduce<<<D, 256, 0, stream>>>(pS, pQ, BN_GRID, gamma1, beta1, scale1, shift1, (float)N);
    gemm_bn<true><<<cdiv(N, 64), 256, 0, stream>>>(emb, x_index, scale1, shift1, W1, bufA, N);
    // agg1 also produces layer-2 BN partials (fused bn_stats)
    agg_kernel<true><<<AGG_GRID, 256, 0, stream>>>((const unsigned int*)bufA, csr, offs,
                                                   (const float2*)b1, (float2*)bufB, N, pS, pQ,
                                                   AGG_GRID);

    // ---- layer 2 ----
    bn_reduce<<<D, 256, 0, stream>>>(pS, pQ, AGG_GRID, gamma2, beta2, scale2, shift2, (float)N);
    gemm_bn<false><<<cdiv(N, 64), 256, 0, stream>>>(bufB, nullptr, scale2, shift2, W2, bufA, N);
    agg_kernel<false><<<cdiv(N, 4), 256, 0, stream>>>((const unsigned int*)bufA, csr, offs,
                                                      (const float2*)b2, (float2*)bufB, N,
                                                      nullptr, nullptr, 0);

    // ---- softmax pooling ----
    pool_kernel<<<G, 1024, 0, stream>>>(tfidf, batch, bufB, out, N);
}

// Round 10
// 354.206 us; speedup vs baseline: 1.1139x; 1.1139x over previous
//
#include <hip/hip_runtime.h>
#include <hip/hip_bf16.h>

#define D 128
#define EPSV 1e-5f

static inline int cdiv(int a, int b) { return (a + b - 1) / b; }

// bf16 RNE pack
__device__ __forceinline__ unsigned short f2bf(float f) {
    unsigned int x = __float_as_uint(f);
    unsigned int r = x + 0x7fffu + ((x >> 16) & 1u);
    return (unsigned short)(r >> 16);
}

// ---------------- edge preprocessing (fully deterministic) ----------------

__global__ void hist_kernel(const int* __restrict__ col, int* __restrict__ cnt, int E_) {
    int e = blockIdx.x * blockDim.x + threadIdx.x;
    if (e >= E_) return;
    atomicAdd(&cnt[col[e]], 1);  // int atomics: result order-independent
}

__global__ void scan_chunk_sums(const int* __restrict__ cnt, int* __restrict__ bsum, int n) {
    __shared__ int sm[1024];
    int i = blockIdx.x * 1024 + threadIdx.x;
    sm[threadIdx.x] = (i < n) ? cnt[i] : 0;
    __syncthreads();
    for (int off = 512; off > 0; off >>= 1) {
        if (threadIdx.x < off) sm[threadIdx.x] += sm[threadIdx.x + off];
        __syncthreads();
    }
    if (threadIdx.x == 0) bsum[blockIdx.x] = sm[0];
}

__global__ void scan_final(const int* __restrict__ cnt, const int* __restrict__ bsum, int nbk,
                           int* __restrict__ offs, int* __restrict__ cursor, int n, int E_) {
    __shared__ int sm[1024];
    __shared__ int sbo;
    int tid = threadIdx.x;
    int bv = (tid < nbk && tid < blockIdx.x) ? bsum[tid] : 0;
    sm[tid] = bv;
    __syncthreads();
    for (int off = 512; off > 0; off >>= 1) {
        if (tid < off) sm[tid] += sm[tid + off];
        __syncthreads();
    }
    if (tid == 0) {
        sbo = sm[0];
        if (blockIdx.x == 0) offs[n] = E_;
    }
    __syncthreads();
    int i = blockIdx.x * 1024 + tid;
    int v = (i < n) ? cnt[i] : 0;
    sm[tid] = v;
    __syncthreads();
    for (int off = 1; off < 1024; off <<= 1) {
        int t = (tid >= off) ? sm[tid - off] : 0;
        __syncthreads();
        sm[tid] += t;
        __syncthreads();
    }
    if (i < n) {
        int excl = sm[tid] - v + sbo;
        offs[i] = excl;
        cursor[i] = excl;
    }
}

// scatter packed (edge_id<<32 | src_row) into CSR slots
__global__ void scatter_pack(const int* __restrict__ row, const int* __restrict__ col,
                             int* __restrict__ cursor, long long* __restrict__ pk, int E_) {
    int e = blockIdx.x * blockDim.x + threadIdx.x;
    if (e >= E_) return;
    int c = col[e];
    int r = row[e];
    int p = atomicAdd(&cursor[c], 1);
    pk[p] = ((long long)e << 32) | (unsigned int)r;
}

// wave-level bitonic sort per node (key = edge id); writes csr=(r, ea),
// deterministic tree-sum for deg -> dis.
__global__ __launch_bounds__(256) void sort_deg_kernel(const long long* __restrict__ pk,
                                                       const int* __restrict__ offs,
                                                       const float* __restrict__ ea,
                                                       float* __restrict__ dis,
                                                       int2* __restrict__ csr, int n) {
    int node = blockIdx.x * 4 + (threadIdx.x >> 6);
    int lane = threadIdx.x & 63;
    if (node >= n) return;
    int p0 = offs[node], p1 = offs[node + 1];
    int deg = p1 - p0;
    if (deg <= 64) {
        long long v = (lane < deg) ? pk[p0 + lane] : 0x7fffffffffffffffLL;
        for (int k = 2; k <= 64; k <<= 1) {
            for (int j = k >> 1; j > 0; j >>= 1) {
                long long partner = __shfl_xor(v, j, 64);
                bool up = ((lane & k) == 0);
                bool keepMin = ((lane & j) == 0);
                long long mn = v < partner ? v : partner;
                long long mx = v < partner ? partner : v;
                v = (up == keepMin) ? mn : mx;
            }
        }
        int e = (int)(v >> 32);
        int r = (int)(v & 0xffffffffLL);
        float av = (lane < deg) ? ea[e] : 0.f;
        if (lane < deg) csr[p0 + lane] = make_int2(r, __float_as_int(av));
        float s = av;
        for (int off = 32; off > 0; off >>= 1) s += __shfl_xor(s, off, 64);
        if (lane == 0) dis[node] = s > 0.f ? rsqrtf(fmaxf(s, EPSV)) : 0.f;
    } else {
        if (lane == 0) {  // deterministic O(d^2) selection fallback (unreachable)
            float dg = 0.f;
            for (int p = p0; p < p1; ++p) {
                long long best = 0x7fffffffffffffffLL;
                for (int q2 = p0; q2 < p1; ++q2) {
                    long long cand = pk[q2];
                    int less = 0;
                    for (int q3 = p0; q3 < p1; ++q3)
                        if (pk[q3] < cand) ++less;
                    if (less == p - p0) { best = cand; break; }
                }
                int e = (int)(best >> 32);
                int r = (int)(best & 0xffffffffLL);
                float av = ea[e];
                csr[p] = make_int2(r, __float_as_int(av));
                dg += av;
            }
            dis[node] = dg > 0.f ? rsqrtf(fmaxf(dg, EPSV)) : 0.f;
        }
    }
}

// finalize weights: (r, ea) -> (r, dis[r]*ea*dis[c])
__global__ __launch_bounds__(256) void fill_w_kernel(const int* __restrict__ offs,
                                                     const float* __restrict__ dis,
                                                     int2* __restrict__ csr, int n) {
    int node = blockIdx.x * 4 + (threadIdx.x >> 6);
    int lane = threadIdx.x & 63;
    if (node >= n) return;
    int p0 = offs[node], p1 = offs[node + 1];
    float dc = dis[node];
    for (int p = p0 + lane; p < p1; p += 64) {
        int2 pr = csr[p];
        float w = dis[pr.x] * __int_as_float(pr.y) * dc;
        csr[p] = make_int2(pr.x, __float_as_int(w));
    }
}

// ---------------- batch norm stats (layer 1: emb gather) ----------------

template <bool GATHER>
__global__ __launch_bounds__(256) void bn_stats(const float* __restrict__ src,
                                                const int* __restrict__ idx,
                                                float* __restrict__ pS,
                                                float* __restrict__ pQ, int n, int NB) {
    int sub = threadIdx.x >> 5;
    int q = threadIdx.x & 31;
    float4 s = make_float4(0, 0, 0, 0), s2 = make_float4(0, 0, 0, 0);
    int stride = gridDim.x * 8;
    int i = blockIdx.x * 8 + sub;
    int r_next = (i < n) ? (GATHER ? idx[i] : i) : 0;
    for (; i < n; i += stride) {
        int r = r_next;
        int i2 = i + stride;
        if (i2 < n) r_next = GATHER ? idx[i2] : i2;
        float4 v = *(const float4*)&src[(long)r * D + q * 4];
        s.x += v.x; s.y += v.y; s.z += v.z; s.w += v.w;
        s2.x += v.x * v.x; s2.y += v.y * v.y; s2.z += v.z * v.z; s2.w += v.w * v.w;
    }
    __shared__ float4 redA[256], redB[256];
    redA[threadIdx.x] = s;
    redB[threadIdx.x] = s2;
    __syncthreads();
    for (int off = 128; off >= 32; off >>= 1) {
        if (threadIdx.x < off) {
            float4 a = redA[threadIdx.x + off], b = redB[threadIdx.x + off];
            redA[threadIdx.x].x += a.x; redA[threadIdx.x].y += a.y;
            redA[threadIdx.x].z += a.z; redA[threadIdx.x].w += a.w;
            redB[threadIdx.x].x += b.x; redB[threadIdx.x].y += b.y;
            redB[threadIdx.x].z += b.z; redB[threadIdx.x].w += b.w;
        }
        __syncthreads();
    }
    if (threadIdx.x < 32) {
        float4 a = redA[threadIdx.x], b = redB[threadIdx.x];
        int bofs = blockIdx.x;
        pS[(q * 4 + 0) * NB + bofs] = a.x;
        pS[(q * 4 + 1) * NB + bofs] = a.y;
        pS[(q * 4 + 2) * NB + bofs] = a.z;
        pS[(q * 4 + 3) * NB + bofs] = a.w;
        pQ[(q * 4 + 0) * NB + bofs] = b.x;
        pQ[(q * 4 + 1) * NB + bofs] = b.y;
        pQ[(q * 4 + 2) * NB + bofs] = b.z;
        pQ[(q * 4 + 3) * NB + bofs] = b.w;
    }
}

__global__ __launch_bounds__(256) void bn_reduce(const float* __restrict__ pS,
                                                 const float* __restrict__ pQ, int nb,
                                                 const float* __restrict__ gamma,
                                                 const float* __restrict__ beta,
                                                 float* __restrict__ scale,
                                                 float* __restrict__ shift, float n) {
    int d = blockIdx.x;
    int tid = threadIdx.x;
    float s = 0.f, q = 0.f;
    for (int b = tid; b < nb; b += 256) {
        s += pS[d * nb + b];
        q += pQ[d * nb + b];
    }
    __shared__ float smS[256], smQ[256];
    smS[tid] = s;
    smQ[tid] = q;
    __syncthreads();
    for (int off = 128; off > 0; off >>= 1) {
        if (tid < off) {
            smS[tid] += smS[tid + off];
            smQ[tid] += smQ[tid + off];
        }
        __syncthreads();
    }
    if (tid == 0) {
        float mean = smS[0] / n;
        float var = smQ[0] / n - mean * mean;
        float rstd = rsqrtf(var + EPSV);
        float sc = gamma[d] * rstd;
        scale[d] = sc;
        shift[d] = beta[d] - mean * sc;
    }
}

// ---------------- GEMM: h = (src*scale+shift) @ W, output bf16 ----------------

template <bool GATHER>
__global__ __launch_bounds__(256) void gemm_bn(const float* __restrict__ src,
                                               const int* __restrict__ idx,
                                               const float* __restrict__ scale,
                                               const float* __restrict__ shift,
                                               const float* __restrict__ W,
                                               unsigned short* __restrict__ outb, int n) {
    __shared__ float xs[64 * 132];  // 33.8 KB
    int tid = threadIdx.x;
    int r0 = blockIdx.x * 64;
    const float4* scale4 = (const float4*)scale;
    const float4* shift4 = (const float4*)shift;
    for (int it = 0; it < 8; ++it) {
        int flat = it * 256 + tid;
        int r = flat >> 5;
        int kq = flat & 31;
        int gr = r0 + r;
        float4 v = make_float4(0.f, 0.f, 0.f, 0.f);
        if (gr < n) {
            int srow = GATHER ? idx[gr] : gr;
            float4 x4 = *(const float4*)&src[(long)srow * D + kq * 4];
            float4 sc = scale4[kq], sh = shift4[kq];
            v = make_float4(x4.x * sc.x + sh.x, x4.y * sc.y + sh.y, x4.z * sc.z + sh.z,
                            x4.w * sc.w + sh.w);
        }
        *(float4*)&xs[r * 132 + kq * 4] = v;
    }
    __syncthreads();
    int cg = tid & 31;
    int rg = tid >> 5;
    float acc[8][4];
#pragma unroll
    for (int j = 0; j < 8; ++j)
#pragma unroll
        for (int q = 0; q < 4; ++q) acc[j][q] = 0.f;
    const float4* Wv = (const float4*)W;
#pragma unroll 2
    for (int k4 = 0; k4 < 128; k4 += 4) {
        float4 wv0 = Wv[(k4 + 0) * 32 + cg];
        float4 wv1 = Wv[(k4 + 1) * 32 + cg];
        float4 wv2 = Wv[(k4 + 2) * 32 + cg];
        float4 wv3 = Wv[(k4 + 3) * 32 + cg];
#pragma unroll
        for (int j = 0; j < 8; ++j) {
            float4 xv = *(const float4*)&xs[(rg * 8 + j) * 132 + k4];
            acc[j][0] += xv.x * wv0.x; acc[j][1] += xv.x * wv0.y;
            acc[j][2] += xv.x * wv0.z; acc[j][3] += xv.x * wv0.w;
            acc[j][0] += xv.y * wv1.x; acc[j][1] += xv.y * wv1.y;
            acc[j][2] += xv.y * wv1.z; acc[j][3] += xv.y * wv1.w;
            acc[j][0] += xv.z * wv2.x; acc[j][1] += xv.z * wv2.y;
            acc[j][2] += xv.z * wv2.z; acc[j][3] += xv.z * wv2.w;
            acc[j][0] += xv.w * wv3.x; acc[j][1] += xv.w * wv3.y;
            acc[j][2] += xv.w * wv3.z; acc[j][3] += xv.w * wv3.w;
        }
    }
#pragma unroll
    for (int j = 0; j < 8; ++j) {
        int gr = r0 + rg * 8 + j;
        if (gr < n) {
            ushort4 o = make_ushort4(f2bf(acc[j][0]), f2bf(acc[j][1]), f2bf(acc[j][2]),
                                     f2bf(acc[j][3]));
            *(ushort4*)&outb[(long)gr * D + cg * 4] = o;
        }
    }
}

// ---------------- aggregation: x[i] = relu(b + sum_e w_e * h[row_e]) ----------------
// ONE memory op per edge: the wave loads its csr chunk once (coalesced,
// csr[base+lane]), then per edge extracts (r,w) via __shfl (readlane -> SGPR
// address path). 4-wide predicated inner loop keeps 4 gathers in flight;
// dummies clamp to edge 0 of the chunk (same row -> L1 hit, weight 0).
// STATS variant accumulates next layer's BN partials.

template <bool STATS>
__global__ __launch_bounds__(256) void agg_kernel(const unsigned int* __restrict__ hw,
                                                  const int2* __restrict__ csr,
                                                  const int* __restrict__ offs,
                                                  const float2* __restrict__ bias2,
                                                  float2* __restrict__ xout, int n,
                                                  float* __restrict__ pS,
                                                  float* __restrict__ pQ, int NB) {
    int lane = threadIdx.x & 63;
    int wv = threadIdx.x >> 6;
    float2 bs = bias2[lane];
    float2 s = make_float2(0.f, 0.f), s2 = make_float2(0.f, 0.f);
    int nGroups = (n + 3) >> 2;
    for (int grp = blockIdx.x; grp < nGroups; grp += gridDim.x) {
        int node = grp * 4 + wv;
        if (node < n) {
            int p0 = offs[node], p1 = offs[node + 1];
            float2 acc = bs;
            for (int base = p0; base < p1; base += 64) {
                int cnt = p1 - base;
                if (cnt > 64) cnt = 64;
                int2 e = csr[base + (lane < cnt ? lane : cnt - 1)];
                for (int j = 0; j < cnt; j += 4) {
#pragma unroll
                    for (int u = 0; u < 4; ++u) {
                        int jj = j + u;
                        bool ok = jj < cnt;
                        int sel = ok ? jj : 0;
                        int r = __shfl(e.x, sel, 64);
                        float w = ok ? __int_as_float(__shfl(e.y, sel, 64)) : 0.f;
                        unsigned int uu = hw[(long)r * 64 + lane];
                        acc.x += w * __uint_as_float(uu << 16);
                        acc.y += w * __uint_as_float(uu & 0xffff0000u);
                    }
                }
            }
            float2 x = make_float2(fmaxf(acc.x, 0.f), fmaxf(acc.y, 0.f));
            xout[(long)node * 64 + lane] = x;
            if (STATS) {
                s.x += x.x; s.y += x.y;
                s2.x += x.x * x.x; s2.y += x.y * x.y;
            }
        }
    }
    if (STATS) {
        __shared__ float2 smS[256], smQ[256];
        smS[threadIdx.x] = s;
        smQ[threadIdx.x] = s2;
        __syncthreads();
        if (wv == 0) {
            float2 a = smS[lane], q = smQ[lane];
#pragma unroll
            for (int w2 = 1; w2 < 4; ++w2) {
                float2 b = smS[w2 * 64 + lane], c = smQ[w2 * 64 + lane];
                a.x += b.x; a.y += b.y;
                q.x += c.x; q.y += c.y;
            }
            pS[(2 * lane + 0) * NB + blockIdx.x] = a.x;
            pS[(2 * lane + 1) * NB + blockIdx.x] = a.y;
            pQ[(2 * lane + 0) * NB + blockIdx.x] = q.x;
            pQ[(2 * lane + 1) * NB + blockIdx.x] = q.y;
        }
    }
}

// ---------------- softmax pooling (bounds in-block, 1024 threads) ----------------

__global__ __launch_bounds__(1024) void pool_kernel(const float* __restrict__ tfidf,
                                                    const int* __restrict__ batch,
                                                    const float* __restrict__ x,
                                                    float* __restrict__ out, int n) {
    int g = blockIdx.x;
    int tid = threadIdx.x;
    __shared__ int sbounds[2];
    if (tid < 2) {
        int target = g + tid;
        int lo = 0, hi = n;
        while (lo < hi) {
            int mid = (lo + hi) >> 1;
            if (batch[mid] < target) lo = mid + 1;
            else hi = mid;
        }
        sbounds[tid] = lo;
    }
    __syncthreads();
    int s0 = sbounds[0], s1 = sbounds[1];
    int d = tid & 127, sub = tid >> 7;  // 8-way node split
    __shared__ float red[1024];
    float m = -1e30f;
    for (int i = s0 + tid; i < s1; i += 1024) m = fmaxf(m, tfidf[i]);
    red[tid] = m;
    __syncthreads();
    for (int off = 512; off > 0; off >>= 1) {
        if (tid < off) red[tid] = fmaxf(red[tid], red[tid + off]);
        __syncthreads();
    }
    m = red[0];
    __syncthreads();
    float s = 0.f;
    for (int i = s0 + tid; i < s1; i += 1024) s += __expf(tfidf[i] - m);
    red[tid] = s;
    __syncthreads();
    for (int off = 512; off > 0; off >>= 1) {
        if (tid < off) red[tid] += red[tid + off];
        __syncthreads();
    }
    s = red[0];
    __syncthreads();
    float acc = 0.f;
    for (int i = s0 + sub; i < s1; i += 8) acc += __expf(tfidf[i] - m) * x[(long)i * D + d];
    red[tid] = acc;
    __syncthreads();
    if (tid < 128) {
        float a = 0.f;
#pragma unroll
        for (int w = 0; w < 8; ++w) a += red[w * 128 + d];
        out[g * D + d] = (s1 > s0) ? a / s : 0.f;
    }
}

// ---------------- launch ----------------

extern "C" void kernel_launch(void* const* d_in, const int* in_sizes, int n_in, void* d_out,
                              int out_size, void* d_ws, size_t ws_size, hipStream_t stream) {
    const int N = in_sizes[0];
    const int E = in_sizes[4];
    const int G = out_size / D;
    const int BN_GRID = 768;
    const int AGG_GRID = 2048;

    const int* x_index = (const int*)d_in[0];
    const float* tfidf = (const float*)d_in[1];
    const int* ei_row = (const int*)d_in[2];
    const int* ei_col = ei_row + E;
    const int* batch = (const int*)d_in[3];
    const float* edge_attr = (const float*)d_in[4];
    const float* emb = (const float*)d_in[5];
    const float* gamma1 = (const float*)d_in[6];
    const float* beta1 = (const float*)d_in[7];
    const float* W1 = (const float*)d_in[8];
    const float* b1 = (const float*)d_in[9];
    const float* gamma2 = (const float*)d_in[10];
    const float* beta2 = (const float*)d_in[11];
    const float* W2 = (const float*)d_in[12];
    const float* b2 = (const float*)d_in[13];
    float* out = (float*)d_out;

    // ---- workspace carve (256B aligned) ----
    size_t off = 0;
    char* base = (char*)d_ws;
    auto carve = [&](size_t bytes) -> void* {
        void* p = base + off;
        off = (off + bytes + 255) & ~(size_t)255;
        return p;
    };
    unsigned short* bufA = (unsigned short*)carve((size_t)N * D * 2);  // h (bf16)
    float* bufB = (float*)carve((size_t)N * D * 4);                    // x (layer output)
    long long* pk = (long long*)carve((size_t)E * 8);                  // packed (e, row)
    int2* csr = (int2*)carve((size_t)E * 8);                           // (row, ea) -> (row, w)
    int* cnt = (int*)carve((size_t)N * 4);                             // zeroed each launch
    float* dis = (float*)carve((size_t)N * 4);
    int* offs = (int*)carve((size_t)(N + 1) * 4);
    int* cursor = (int*)carve((size_t)N * 4);
    int* bsum = (int*)carve(64 * 4);
    float* scale1 = (float*)carve(D * 4);
    float* shift1 = (float*)carve(D * 4);
    float* scale2 = (float*)carve(D * 4);
    float* shift2 = (float*)carve(D * 4);
    float* pS = (float*)carve((size_t)AGG_GRID * D * 4);
    float* pQ = (float*)carve((size_t)AGG_GRID * D * 4);
    (void)ws_size;
    (void)n_in;

    hipMemsetAsync(cnt, 0, (size_t)N * 4, stream);

    // ---- edge preprocessing: CSR (deterministic; shared by both layers) ----
    hist_kernel<<<cdiv(E, 256), 256, 0, stream>>>(ei_col, cnt, E);
    int nb = cdiv(N, 1024);
    scan_chunk_sums<<<nb, 1024, 0, stream>>>(cnt, bsum, N);
    scan_final<<<nb, 1024, 0, stream>>>(cnt, bsum, nb, offs, cursor, N, E);
    scatter_pack<<<cdiv(E, 256), 256, 0, stream>>>(ei_row, ei_col, cursor, pk, E);
    sort_deg_kernel<<<cdiv(N, 4), 256, 0, stream>>>(pk, offs, edge_attr, dis, csr, N);
    fill_w_kernel<<<cdiv(N, 4), 256, 0, stream>>>(offs, dis, csr, N);

    // ---- layer 1 ----
    bn_stats<true><<<BN_GRID, 256, 0, stream>>>(emb, x_index, pS, pQ, N, BN_GRID);
    bn_reduce<<<D, 256, 0, stream>>>(pS, pQ, BN_GRID, gamma1, beta1, scale1, shift1, (float)N);
    gemm_bn<true><<<cdiv(N, 64), 256, 0, stream>>>(emb, x_index, scale1, shift1, W1, bufA, N);
    // agg1 also produces layer-2 BN partials (fused bn_stats)
    agg_kernel<true><<<AGG_GRID, 256, 0, stream>>>((const unsigned int*)bufA, csr, offs,
                                                   (const float2*)b1, (float2*)bufB, N, pS, pQ,
                                                   AGG_GRID);

    // ---- layer 2 ----
    bn_reduce<<<D, 256, 0, stream>>>(pS, pQ, AGG_GRID, gamma2, beta2, scale2, shift2, (float)N);
    gemm_bn<false><<<cdiv(N, 64), 256, 0, stream>>>(bufB, nullptr, scale2, shift2, W2, bufA, N);
    agg_kernel<false><<<cdiv(N, 4), 256, 0, stream>>>((const unsigned int*)bufA, csr, offs,
                                                      (const float2*)b2, (float2*)bufB, N,
                                                      nullptr, nullptr, 0);

    // ---- softmax pooling ----
    pool_kernel<<<G, 1024, 0, stream>>>(tfidf, batch, bufB, out, N);
}